// Round 6
// baseline (62.115 us; speedup 1.0000x reference)
//
#include <hip/hip_runtime.h>
#include <hip/hip_bf16.h>

// okl = log_C_kappa + kappa + mean_j log( sum_i exp(kappa*<mu_n_i,z_j> - kappa) )
//       - log(M) - log_C_zero
// M = 2048 components, J = 65536 sample columns, d = 32.
//
// Schraudolph epilogue: A pre-scaled by kappa*log2e*2^23; MFMA C-operand holds
// (BIAS-S)*2^23 + MAGIC so int-truncation of the MFMA output is the IEEE bit
// pattern of 2^(score-S+BIAS). Per element: v_max, v_cvt_i32, v_add.
//
// ROUND 6: A/B in one launch. V1 (512 blk x 512 thr, 128 cols) -> dummy part2.
// V2 (2048 blk x 256 thr, 32 cols, 32 waves/CU full occupancy) -> real part.
// V2 cost = total - 36.8 (R5 baseline).

typedef __attribute__((ext_vector_type(8))) short bf16x8;
typedef __attribute__((ext_vector_type(4))) float f32x4;
typedef __attribute__((ext_vector_type(8))) unsigned short u16x8;

#define LOG2E 1.44269504088896340736
#define LN2F 0.6931471805599453f
#define BIAS 48.0
// 127*2^23 - D, D = 471400 (mean-log-centered linear-mantissa exp2)
#define MAGIC 1064881816.0
#define CLAMPF 8388608.0f   // 2^23: result exponent floor -> 2^-126, no wrap

static __device__ __forceinline__ unsigned short f2bf(float f) {
  unsigned int u = __float_as_uint(f);
  u += 0x7FFFu + ((u >> 16) & 1u);   // round-to-nearest-even
  return (unsigned short)(u >> 16);
}

// Kernel 1: Abf = bf16(kappa*log2e*2^23 * mu / ||mu||), shape [M, 32].
__global__ __launch_bounds__(64) void vmf_prep(const float* __restrict__ mu,
                                               const float* __restrict__ kp,
                                               unsigned short* __restrict__ Abf,
                                               int M) {
  int row = blockIdx.x * 64 + threadIdx.x;
  if (row >= M) return;
  const float4* m4 = (const float4*)(mu + (size_t)row * 32);
  float4 v[8];
  float ss = 0.f;
#pragma unroll
  for (int i = 0; i < 8; ++i) {
    v[i] = m4[i];
    ss += v[i].x * v[i].x + v[i].y * v[i].y + v[i].z * v[i].z + v[i].w * v[i].w;
  }
  float sc = (float)((double)kp[0] * LOG2E * 8388608.0) / sqrtf(ss);
  u16x8 o[4];
#pragma unroll
  for (int i = 0; i < 8; ++i) {
    o[i >> 1][(i & 1) * 4 + 0] = f2bf(v[i].x * sc);
    o[i >> 1][(i & 1) * 4 + 1] = f2bf(v[i].y * sc);
    o[i >> 1][(i & 1) * 4 + 2] = f2bf(v[i].z * sc);
    o[i >> 1][(i & 1) * 4 + 3] = f2bf(v[i].w * sc);
  }
  u16x8* dst = (u16x8*)(Abf + (size_t)row * 32);
#pragma unroll
  for (int i = 0; i < 4; ++i) dst[i] = o[i];
}

// V1: block = 128 columns (8 N-tiles) x 8 waves, wave covers M/8 rows.
__global__ __launch_bounds__(512) void vmf_main(const unsigned short* __restrict__ Abf,
                                                const float* __restrict__ z,
                                                const float* __restrict__ kp,
                                                float* __restrict__ part,
                                                int M) {
  const int lane = threadIdx.x & 63;
  const int wave = threadIdx.x >> 6;   // 0..7
  const int r = lane & 15;
  const int q = lane >> 4;
  const float ci = (float)((BIAS - (double)kp[0] * LOG2E) * 8388608.0 + MAGIC);
  const f32x4 cinit = {ci, ci, ci, ci};
  const int colbase = blockIdx.x * 128;

  bf16x8 b[8];
#pragma unroll
  for (int t = 0; t < 8; ++t) {
    const float* zp = z + (size_t)(colbase + t * 16 + r) * 32 + q * 8;
    float4 fa = *(const float4*)zp;
    float4 fb = *(const float4*)(zp + 4);
    b[t][0] = (short)f2bf(fa.x); b[t][1] = (short)f2bf(fa.y);
    b[t][2] = (short)f2bf(fa.z); b[t][3] = (short)f2bf(fa.w);
    b[t][4] = (short)f2bf(fb.x); b[t][5] = (short)f2bf(fb.y);
    b[t][6] = (short)f2bf(fb.z); b[t][7] = (short)f2bf(fb.w);
  }

  const int mchunk = M >> 3;           // 256
  const unsigned short* ap = Abf + (size_t)(wave * mchunk + r) * 32 + q * 8;
  bf16x8 av = *(const bf16x8*)ap;
  float acc[8] = {0.f, 0.f, 0.f, 0.f, 0.f, 0.f, 0.f, 0.f};
  for (int m = 0; m < mchunk; m += 16) {
    const int mn = (m + 16) & (mchunk - 1);
    bf16x8 nxt = *(const bf16x8*)(ap + (size_t)mn * 32);
#pragma unroll
    for (int t = 0; t < 8; ++t) {
      f32x4 c = __builtin_amdgcn_mfma_f32_16x16x32_bf16(av, b[t], cinit, 0, 0, 0);
#pragma unroll
      for (int e = 0; e < 4; ++e) {
        float cf = fmaxf(c[e], CLAMPF);
        acc[t] += __int_as_float((int)cf);
      }
    }
    av = nxt;
  }

#pragma unroll
  for (int t = 0; t < 8; ++t) {
    acc[t] += __shfl_xor(acc[t], 16);
    acc[t] += __shfl_xor(acc[t], 32);
  }
  float vlo = (q == 0) ? acc[0] : (q == 1) ? acc[1] : (q == 2) ? acc[2] : acc[3];
  float vhi = (q == 0) ? acc[4] : (q == 1) ? acc[5] : (q == 2) ? acc[6] : acc[7];

  __shared__ float rlo[8][64];
  __shared__ float rhi[8][64];
  rlo[wave][lane] = vlo;
  rhi[wave][lane] = vhi;
  __syncthreads();

  if (wave == 0) {
    float slo = 0.f, shi = 0.f;
#pragma unroll
    for (int w = 0; w < 8; ++w) { slo += rlo[w][lane]; shi += rhi[w][lane]; }
    slo = fmaxf(slo, 1e-38f);
    shi = fmaxf(shi, 1e-38f);
    float t = __logf(slo) + __logf(shi);
    t += __shfl_xor(t, 1);  t += __shfl_xor(t, 2);
    t += __shfl_xor(t, 4);  t += __shfl_xor(t, 8);
    t += __shfl_xor(t, 16); t += __shfl_xor(t, 32);
    if (lane == 0) part[blockIdx.x] = t;
  }
}

// V2: block = 32 columns (2 N-tiles) x 4 waves (256 thr), wave covers M/4
// rows. VGPR ~32, LDS 2 KB -> 8 blocks/CU = 32 waves/CU (full occupancy).
__global__ __launch_bounds__(256) void vmf_main2(const unsigned short* __restrict__ Abf,
                                                 const float* __restrict__ z,
                                                 const float* __restrict__ kp,
                                                 float* __restrict__ part,
                                                 int M) {
  const int lane = threadIdx.x & 63;
  const int wave = threadIdx.x >> 6;   // 0..3
  const int r = lane & 15;
  const int q = lane >> 4;
  const float ci = (float)((BIAS - (double)kp[0] * LOG2E) * 8388608.0 + MAGIC);
  const f32x4 cinit = {ci, ci, ci, ci};
  const int colbase = blockIdx.x * 32;

  bf16x8 b[2];
#pragma unroll
  for (int t = 0; t < 2; ++t) {
    const float* zp = z + (size_t)(colbase + t * 16 + r) * 32 + q * 8;
    float4 fa = *(const float4*)zp;
    float4 fb = *(const float4*)(zp + 4);
    b[t][0] = (short)f2bf(fa.x); b[t][1] = (short)f2bf(fa.y);
    b[t][2] = (short)f2bf(fa.z); b[t][3] = (short)f2bf(fa.w);
    b[t][4] = (short)f2bf(fb.x); b[t][5] = (short)f2bf(fb.y);
    b[t][6] = (short)f2bf(fb.z); b[t][7] = (short)f2bf(fb.w);
  }

  const int mchunk = M >> 2;           // 512 (power of 2)
  const unsigned short* ap = Abf + (size_t)(wave * mchunk + r) * 32 + q * 8;
  bf16x8 av = *(const bf16x8*)ap;
  float a0 = 0.f, a1 = 0.f;
  for (int m = 0; m < mchunk; m += 16) {
    const int mn = (m + 16) & (mchunk - 1);
    bf16x8 nxt = *(const bf16x8*)(ap + (size_t)mn * 32);
    f32x4 c0 = __builtin_amdgcn_mfma_f32_16x16x32_bf16(av, b[0], cinit, 0, 0, 0);
    f32x4 c1 = __builtin_amdgcn_mfma_f32_16x16x32_bf16(av, b[1], cinit, 0, 0, 0);
#pragma unroll
    for (int e = 0; e < 4; ++e) {
      a0 += __int_as_float((int)fmaxf(c0[e], CLAMPF));
      a1 += __int_as_float((int)fmaxf(c1[e], CLAMPF));
    }
    av = nxt;
  }

  a0 += __shfl_xor(a0, 16); a0 += __shfl_xor(a0, 32);
  a1 += __shfl_xor(a1, 16); a1 += __shfl_xor(a1, 32);
  // col = (q&1)*16 + r; q in {0,2} and {1,3} write duplicate (equal) values.
  float v = (q & 1) ? a1 : a0;
  __shared__ float red[4][32];
  red[wave][(q & 1) * 16 + r] = v;
  __syncthreads();

  if (wave == 0 && lane < 32) {
    float s = red[0][lane] + red[1][lane] + red[2][lane] + red[3][lane];
    s = fmaxf(s, 1e-38f);
    float t = __logf(s);
    t += __shfl_xor(t, 1); t += __shfl_xor(t, 2);
    t += __shfl_xor(t, 4); t += __shfl_xor(t, 8);
    t += __shfl_xor(t, 16);
    if (lane == 0) part[blockIdx.x] = t;   // sum over this block's 32 columns
  }
}

// Kernel 3: reduce per-block partials, apply constants (incl. -BIAS*ln2).
__global__ __launch_bounds__(256) void vmf_final(const float* __restrict__ part, int n,
                                                 const float* __restrict__ kp,
                                                 const float* __restrict__ lck,
                                                 const float* __restrict__ lc0,
                                                 float* __restrict__ out,
                                                 int M, int J) {
  __shared__ float red[256];
  float s = 0.f;
  for (int i = threadIdx.x; i < n; i += 256) s += part[i];
  red[threadIdx.x] = s;
  __syncthreads();
  for (int off = 128; off > 0; off >>= 1) {
    if (threadIdx.x < off) red[threadIdx.x] += red[threadIdx.x + off];
    __syncthreads();
  }
  if (threadIdx.x == 0) {
    float tbar = red[0] / (float)J - (float)BIAS * LN2F;
    out[0] = lck[0] + kp[0] + tbar - logf((float)M) - lc0[0];
  }
}

extern "C" void kernel_launch(void* const* d_in, const int* in_sizes, int n_in,
                              void* d_out, int out_size, void* d_ws, size_t ws_size,
                              hipStream_t stream) {
  const float* mu  = (const float*)d_in[0];
  const float* z   = (const float*)d_in[1];
  const float* kp  = (const float*)d_in[2];
  const float* lck = (const float*)d_in[3];
  const float* lc0 = (const float*)d_in[4];
  const int M = in_sizes[0] / 32;   // 2048
  const int J = in_sizes[1] / 32;   // 65536 (= M * n_samples)

  char* ws = (char*)d_ws;
  unsigned short* Abf = (unsigned short*)ws;                 // M*32*2 = 128 KB
  size_t abytes = ((size_t)M * 32 * 2 + 255) & ~(size_t)255;
  const int nblk2 = J / 32;                                  // 2048 (V2, real)
  const int nblk1 = J / 128;                                 // 512  (V1, dummy)
  float* part  = (float*)(ws + abytes);
  float* part2 = part + nblk2;

  vmf_prep<<<(M + 63) / 64, 64, 0, stream>>>(mu, kp, Abf, M);
  vmf_main<<<nblk1, 512, 0, stream>>>(Abf, z, kp, part2, M);   // V1 -> dummy
  vmf_main2<<<nblk2, 256, 0, stream>>>(Abf, z, kp, part, M);   // V2 -> real
  vmf_final<<<1, 256, 0, stream>>>(part, nblk2, kp, lck, lc0, (float*)d_out, M, J);
}

// Round 7
// 36.462 us; speedup vs baseline: 1.7036x; 1.7036x over previous
//
#include <hip/hip_runtime.h>
#include <hip/hip_bf16.h>

// okl = log_C_kappa + kappa + mean_j log( sum_i exp(kappa*<mu_n_i,z_j> - kappa) )
//       - log(M) - log_C_zero
// M = 2048 components, J = 65536 sample columns, d = 32.
//
// Schraudolph epilogue: A pre-scaled by kappa*log2e*2^23; MFMA C-operand holds
// (BIAS-S)*2^23 + MAGIC so int-truncation of the MFMA output is the IEEE bit
// pattern of 2^(score-S+BIAS). Per element: v_max, v_cvt_i32, v_add.
//
// R7: (1) fully-unrolled M loop: 16 A-frags in 4 groups of 4, 2-stage
// ping-pong prefetch (4 independent loads in flight, static indices).
// (2) no final kernel: prep writes out[0]=C, main blocks atomicAdd t_b/J.

typedef __attribute__((ext_vector_type(8))) short bf16x8;
typedef __attribute__((ext_vector_type(4))) float f32x4;

#define LOG2E 1.44269504088896340736
#define LN2 0.6931471805599453
#define BIAS 48.0
// 127*2^23 - D, D = 471400 (mean-log-centered linear-mantissa exp2)
#define MAGIC 1064881816.0
#define CLAMPF 8388608.0f   // 2^23: result exponent floor -> 2^-126, no wrap

static __device__ __forceinline__ unsigned short f2bf(float f) {
  unsigned int u = __float_as_uint(f);
  u += 0x7FFFu + ((u >> 16) & 1u);   // round-to-nearest-even
  return (unsigned short)(u >> 16);
}

// Kernel 1: Abf = bf16(kappa*log2e*2^23 * mu / ||mu||), 8 lanes per row.
// Thread (0,0) also writes out[0] = all-constant part of okl.
__global__ __launch_bounds__(256) void vmf_prep(const float* __restrict__ mu,
                                                const float* __restrict__ kp,
                                                const float* __restrict__ lck,
                                                const float* __restrict__ lc0,
                                                unsigned short* __restrict__ Abf,
                                                float* __restrict__ out, int M) {
  int tid = blockIdx.x * 256 + threadIdx.x;
  if (tid == 0) {
    out[0] = (float)((double)lck[0] + (double)kp[0] - BIAS * LN2 -
                     log((double)M) - (double)lc0[0]);
  }
  int row = tid >> 3;
  int sub = tid & 7;                  // 4 columns per lane
  if (row >= M) return;
  const float4 v = *(const float4*)(mu + (size_t)row * 32 + sub * 4);
  float ss = v.x * v.x + v.y * v.y + v.z * v.z + v.w * v.w;
  ss += __shfl_xor(ss, 1);
  ss += __shfl_xor(ss, 2);
  ss += __shfl_xor(ss, 4);            // full row norm within 8-lane group
  float sc = (float)((double)kp[0] * LOG2E * 8388608.0) / sqrtf(ss);
  ushort4 o;
  o.x = f2bf(v.x * sc); o.y = f2bf(v.y * sc);
  o.z = f2bf(v.z * sc); o.w = f2bf(v.w * sc);
  *(ushort4*)(Abf + (size_t)row * 32 + sub * 4) = o;
}

// Kernel 2 (M == 2048 specialization): block = 128 cols (8 N-tiles) x 8
// waves, wave covers 256 rows = 16 A-frags, fully unrolled with 2-stage
// 4-deep prefetch. Block reduces to t_b, atomicAdds t_b/J into out[0].
__global__ __launch_bounds__(512) void vmf_main(const unsigned short* __restrict__ Abf,
                                                const float* __restrict__ z,
                                                const float* __restrict__ kp,
                                                float* __restrict__ out, int J) {
  const int lane = threadIdx.x & 63;
  const int wave = threadIdx.x >> 6;   // 0..7
  const int r = lane & 15;
  const int q = lane >> 4;
  const float ci = (float)((BIAS - (double)kp[0] * LOG2E) * 8388608.0 + MAGIC);
  const f32x4 cinit = {ci, ci, ci, ci};
  const int colbase = blockIdx.x * 128;

  // Loop-invariant B fragments (8 tiles), fp32 -> bf16 on the fly.
  bf16x8 b[8];
#pragma unroll
  for (int t = 0; t < 8; ++t) {
    const float* zp = z + (size_t)(colbase + t * 16 + r) * 32 + q * 8;
    float4 fa = *(const float4*)zp;
    float4 fb = *(const float4*)(zp + 4);
    b[t][0] = (short)f2bf(fa.x); b[t][1] = (short)f2bf(fa.y);
    b[t][2] = (short)f2bf(fa.z); b[t][3] = (short)f2bf(fa.w);
    b[t][4] = (short)f2bf(fb.x); b[t][5] = (short)f2bf(fb.y);
    b[t][6] = (short)f2bf(fb.z); b[t][7] = (short)f2bf(fb.w);
  }

  // 2048 rows / 8 waves = 256 rows = 16 frags = 4 groups of 4.
  const unsigned short* ap = Abf + (size_t)(wave * 256 + r) * 32 + q * 8;
  float acc[8] = {0.f, 0.f, 0.f, 0.f, 0.f, 0.f, 0.f, 0.f};
  bf16x8 afA[4], afB[4];
#pragma unroll
  for (int f = 0; f < 4; ++f)
    afA[f] = *(const bf16x8*)(ap + (size_t)(f * 16) * 32);
#pragma unroll
  for (int g = 0; g < 4; ++g) {
    const bf16x8* cur = (g & 1) ? afB : afA;
    bf16x8* nxt = (g & 1) ? afA : afB;
    if (g < 3) {
#pragma unroll
      for (int f = 0; f < 4; ++f)
        nxt[f] = *(const bf16x8*)(ap + (size_t)((g + 1) * 64 + f * 16) * 32);
    }
#pragma unroll
    for (int f = 0; f < 4; ++f) {
#pragma unroll
      for (int t = 0; t < 8; ++t) {
        f32x4 c = __builtin_amdgcn_mfma_f32_16x16x32_bf16(cur[f], b[t], cinit, 0, 0, 0);
#pragma unroll
        for (int e = 0; e < 4; ++e) {
          float cf = fmaxf(c[e], CLAMPF);
          acc[t] += __int_as_float((int)cf);   // Schraudolph exp2
        }
      }
    }
  }

  // Sum the 4 row-quadrants per column (lanes l, l^16, l^32, l^48 share col).
#pragma unroll
  for (int t = 0; t < 8; ++t) {
    acc[t] += __shfl_xor(acc[t], 16);
    acc[t] += __shfl_xor(acc[t], 32);
  }
  float vlo = (q == 0) ? acc[0] : (q == 1) ? acc[1] : (q == 2) ? acc[2] : acc[3];
  float vhi = (q == 0) ? acc[4] : (q == 1) ? acc[5] : (q == 2) ? acc[6] : acc[7];

  __shared__ float rlo[8][64];
  __shared__ float rhi[8][64];
  rlo[wave][lane] = vlo;
  rhi[wave][lane] = vhi;
  __syncthreads();

  if (wave == 0) {
    float slo = 0.f, shi = 0.f;
#pragma unroll
    for (int w = 0; w < 8; ++w) { slo += rlo[w][lane]; shi += rhi[w][lane]; }
    slo = fmaxf(slo, 1e-38f);
    shi = fmaxf(shi, 1e-38f);
    float t = __logf(slo) + __logf(shi);   // 2 columns' t_j for this lane
    t += __shfl_xor(t, 1);  t += __shfl_xor(t, 2);
    t += __shfl_xor(t, 4);  t += __shfl_xor(t, 8);
    t += __shfl_xor(t, 16); t += __shfl_xor(t, 32);
    if (lane == 0) atomicAdd(out, t / (float)J);
  }
}

// Generic fallback (any M multiple of 16): V1-style loop. Only used if
// M != 2048.
__global__ __launch_bounds__(512) void vmf_main_gen(const unsigned short* __restrict__ Abf,
                                                    const float* __restrict__ z,
                                                    const float* __restrict__ kp,
                                                    float* __restrict__ out,
                                                    int M, int J) {
  const int lane = threadIdx.x & 63;
  const int wave = threadIdx.x >> 6;
  const int r = lane & 15;
  const int q = lane >> 4;
  const float ci = (float)((BIAS - (double)kp[0] * LOG2E) * 8388608.0 + MAGIC);
  const f32x4 cinit = {ci, ci, ci, ci};
  const int colbase = blockIdx.x * 128;

  bf16x8 b[8];
#pragma unroll
  for (int t = 0; t < 8; ++t) {
    const float* zp = z + (size_t)(colbase + t * 16 + r) * 32 + q * 8;
    float4 fa = *(const float4*)zp;
    float4 fb = *(const float4*)(zp + 4);
    b[t][0] = (short)f2bf(fa.x); b[t][1] = (short)f2bf(fa.y);
    b[t][2] = (short)f2bf(fa.z); b[t][3] = (short)f2bf(fa.w);
    b[t][4] = (short)f2bf(fb.x); b[t][5] = (short)f2bf(fb.y);
    b[t][6] = (short)f2bf(fb.z); b[t][7] = (short)f2bf(fb.w);
  }

  float acc[8] = {0.f, 0.f, 0.f, 0.f, 0.f, 0.f, 0.f, 0.f};
  for (int m = wave * 16; m < M; m += 128) {
    bf16x8 av = *(const bf16x8*)(Abf + (size_t)(m + r) * 32 + q * 8);
#pragma unroll
    for (int t = 0; t < 8; ++t) {
      f32x4 c = __builtin_amdgcn_mfma_f32_16x16x32_bf16(av, b[t], cinit, 0, 0, 0);
#pragma unroll
      for (int e = 0; e < 4; ++e)
        acc[t] += __int_as_float((int)fmaxf(c[e], CLAMPF));
    }
  }

#pragma unroll
  for (int t = 0; t < 8; ++t) {
    acc[t] += __shfl_xor(acc[t], 16);
    acc[t] += __shfl_xor(acc[t], 32);
  }
  float vlo = (q == 0) ? acc[0] : (q == 1) ? acc[1] : (q == 2) ? acc[2] : acc[3];
  float vhi = (q == 0) ? acc[4] : (q == 1) ? acc[5] : (q == 2) ? acc[6] : acc[7];

  __shared__ float rlo[8][64];
  __shared__ float rhi[8][64];
  rlo[wave][lane] = vlo;
  rhi[wave][lane] = vhi;
  __syncthreads();

  if (wave == 0) {
    float slo = 0.f, shi = 0.f;
#pragma unroll
    for (int w = 0; w < 8; ++w) { slo += rlo[w][lane]; shi += rhi[w][lane]; }
    slo = fmaxf(slo, 1e-38f);
    shi = fmaxf(shi, 1e-38f);
    float t = __logf(slo) + __logf(shi);
    t += __shfl_xor(t, 1);  t += __shfl_xor(t, 2);
    t += __shfl_xor(t, 4);  t += __shfl_xor(t, 8);
    t += __shfl_xor(t, 16); t += __shfl_xor(t, 32);
    if (lane == 0) atomicAdd(out, t / (float)J);
  }
}

extern "C" void kernel_launch(void* const* d_in, const int* in_sizes, int n_in,
                              void* d_out, int out_size, void* d_ws, size_t ws_size,
                              hipStream_t stream) {
  const float* mu  = (const float*)d_in[0];
  const float* z   = (const float*)d_in[1];
  const float* kp  = (const float*)d_in[2];
  const float* lck = (const float*)d_in[3];
  const float* lc0 = (const float*)d_in[4];
  const int M = in_sizes[0] / 32;   // 2048
  const int J = in_sizes[1] / 32;   // 65536 (= M * n_samples)
  float* out = (float*)d_out;

  unsigned short* Abf = (unsigned short*)d_ws;   // M*32*2 = 128 KB

  vmf_prep<<<(M * 8 + 255) / 256, 256, 0, stream>>>(mu, kp, lck, lc0, Abf, out, M);
  const int nblk = J / 128;  // 512 blocks, 8 waves each
  if (M == 2048)
    vmf_main<<<nblk, 512, 0, stream>>>(Abf, z, kp, out, J);
  else
    vmf_main_gen<<<nblk, 512, 0, stream>>>(Abf, z, kp, out, M, J);
}